// Round 2
// baseline (295.369 us; speedup 1.0000x reference)
//
#include <hip/hip_runtime.h>

#define BS 64
#define C 512
#define DIN 256
#define DOUT 256
#define H 4
#define HD 64

typedef __attribute__((ext_vector_type(8))) short short8;
typedef __attribute__((ext_vector_type(4))) float f32x4;

__device__ __forceinline__ short f2bf(float f) {
    union { float f; unsigned u; } v; v.f = f;
    unsigned r = v.u + 0x7fffu + ((v.u >> 16) & 1u);
    return (short)(r >> 16);
}

__device__ __forceinline__ short8 pack8(const float* p) {
    short8 r;
#pragma unroll
    for (int i = 0; i < 8; ++i) r[i] = f2bf(p[i]);
    return r;
}

// K1: Wh = h @ W^T (bf16 MFMA), store WhT[b][h][d][c] bf16 + e_i/e_j[b][h][c] f32
__global__ __launch_bounds__(256) void k1_gemm(
    const float* __restrict__ hsrc, const float* __restrict__ W,
    const float* __restrict__ avec,
    short* __restrict__ whT, float* __restrict__ ei, float* __restrict__ ej)
{
    const int tid = threadIdx.x;
    const int l = tid & 63;
    const int w = tid >> 6;
    const int mtile = blockIdx.x >> 1;
    const int ntile = blockIdx.x & 1;
    const int row_base = mtile * 64 + (w & 1) * 32;     // global row in [0,32768)
    const int col_base = ntile * 128 + (w >> 1) * 64;   // output col in [0,256)
    const int head = col_base >> 6;
    const int lr = l & 15;
    const int kg = (l >> 4) * 8;

    f32x4 acc[2][4];
#pragma unroll
    for (int i = 0; i < 2; ++i)
#pragma unroll
        for (int j = 0; j < 4; ++j) acc[i][j] = f32x4{0.f, 0.f, 0.f, 0.f};

    for (int k0 = 0; k0 < DIN; k0 += 32) {
        short8 af[2];
#pragma unroll
        for (int rt = 0; rt < 2; ++rt) {
            const float* p = hsrc + (size_t)(row_base + rt * 16 + lr) * DIN + k0 + kg;
            float tmp[8];
            *(float4*)(tmp)     = *(const float4*)(p);
            *(float4*)(tmp + 4) = *(const float4*)(p + 4);
            af[rt] = pack8(tmp);
        }
        short8 bfr[4];
#pragma unroll
        for (int ct = 0; ct < 4; ++ct) {
            const float* p = W + (size_t)(col_base + ct * 16 + lr) * DIN + k0 + kg;
            float tmp[8];
            *(float4*)(tmp)     = *(const float4*)(p);
            *(float4*)(tmp + 4) = *(const float4*)(p + 4);
            bfr[ct] = pack8(tmp);
        }
#pragma unroll
        for (int rt = 0; rt < 2; ++rt)
#pragma unroll
            for (int ct = 0; ct < 4; ++ct)
                acc[rt][ct] = __builtin_amdgcn_mfma_f32_16x16x32_bf16(
                    af[rt], bfr[ct], acc[rt][ct], 0, 0, 0);
    }

    float avi[4], avj[4];
#pragma unroll
    for (int ct = 0; ct < 4; ++ct) {
        avi[ct] = avec[head * 2 * HD + ct * 16 + lr];
        avj[ct] = avec[head * 2 * HD + HD + ct * 16 + lr];
    }
#pragma unroll
    for (int rt = 0; rt < 2; ++rt) {
#pragma unroll
        for (int reg = 0; reg < 4; ++reg) {
            const int crow = row_base + rt * 16 + (l >> 4) * 4 + reg;
            const int b = crow >> 9;
            const int c = crow & 511;
            float pi = 0.f, pj = 0.f;
#pragma unroll
            for (int ct = 0; ct < 4; ++ct) {
                const float v = acc[rt][ct][reg];
                pi += v * avi[ct];
                pj += v * avj[ct];
                const int d = ct * 16 + lr;
                whT[((size_t)(b * H + head) * HD + d) * C + c] = f2bf(v);
            }
#pragma unroll
            for (int off = 1; off < 16; off <<= 1) {
                pi += __shfl_xor(pi, off);
                pj += __shfl_xor(pj, off);
            }
            if (lr == 0) {
                ei[(b * H + head) * C + c] = pi;
                ej[(b * H + head) * C + c] = pj;
            }
        }
    }
}

// K2: per (b, 64-row i-tile) block; wave = head. Online softmax + P@V via MFMA.
__global__ __launch_bounds__(256) void k2_attn(
    const float* __restrict__ Afc, const short* __restrict__ whT,
    const float* __restrict__ ei, const float* __restrict__ ej,
    float* __restrict__ hp)
{
    const int tid = threadIdx.x;
    const int l = tid & 63;
    const int hh = tid >> 6;
    const int b = blockIdx.x >> 3;
    const int i0 = (blockIdx.x & 7) * 64;
    const int lr = l & 15;
    const int kg = (l >> 4) * 8;
    const float L2E = 1.44269504088896f;

    f32x4 O[4][4];
#pragma unroll
    for (int is = 0; is < 4; ++is)
#pragma unroll
        for (int dt = 0; dt < 4; ++dt) O[is][dt] = f32x4{0.f, 0.f, 0.f, 0.f};
    float m[4], ll[4];
#pragma unroll
    for (int is = 0; is < 4; ++is) { m[is] = -1e30f; ll[is] = 0.f; }

    float eiv[4];
#pragma unroll
    for (int is = 0; is < 4; ++is)
        eiv[is] = ei[(b * H + hh) * C + i0 + is * 16 + lr];

    const float* ejb = ej + (b * H + hh) * C;
    const short* vb = whT + (size_t)(b * H + hh) * HD * C;

    for (int jt = 0; jt < 8; ++jt) {
        const int j0 = jt * 64;
        float ejv[16];
        *(float4*)(ejv)      = *(const float4*)(ejb + j0 + kg);
        *(float4*)(ejv + 4)  = *(const float4*)(ejb + j0 + kg + 4);
        *(float4*)(ejv + 8)  = *(const float4*)(ejb + j0 + 32 + kg);
        *(float4*)(ejv + 12) = *(const float4*)(ejb + j0 + 32 + kg + 4);

        short8 vf[4][2];
#pragma unroll
        for (int dt = 0; dt < 4; ++dt) {
            const short* p = vb + (size_t)(dt * 16 + lr) * C + j0 + kg;
            vf[dt][0] = *(const short8*)(p);
            vf[dt][1] = *(const short8*)(p + 32);
        }

#pragma unroll
        for (int is = 0; is < 4; ++is) {
            const int i = i0 + is * 16 + lr;
            const float* ap = Afc + ((size_t)b * C + i) * C + j0 + kg;
            float av[16];
            *(float4*)(av)      = *(const float4*)(ap);
            *(float4*)(av + 4)  = *(const float4*)(ap + 4);
            *(float4*)(av + 8)  = *(const float4*)(ap + 32);
            *(float4*)(av + 12) = *(const float4*)(ap + 36);

            float sp[16];
            float tm = -1e30f;
#pragma unroll
            for (int t = 0; t < 16; ++t) {
                float z = eiv[is] + ejv[t];
                z = z > 0.f ? z : 0.2f * z;
                sp[t] = z * av[t];
                tm = fmaxf(tm, sp[t]);
            }
            tm = fmaxf(tm, __shfl_xor(tm, 16));
            tm = fmaxf(tm, __shfl_xor(tm, 32));
            const float mn = fmaxf(m[is], tm);
            const float scale = exp2f((m[is] - mn) * L2E);
            m[is] = mn;
            float ps = 0.f;
#pragma unroll
            for (int t = 0; t < 16; ++t) {
                sp[t] = exp2f((sp[t] - mn) * L2E);
                ps += sp[t];
            }
            ps += __shfl_xor(ps, 16);
            ps += __shfl_xor(ps, 32);
            ll[is] = ll[is] * scale + ps;

            float fr[4];
#pragma unroll
            for (int reg = 0; reg < 4; ++reg)
                fr[reg] = __shfl(scale, (l >> 4) * 4 + reg);
#pragma unroll
            for (int dt = 0; dt < 4; ++dt)
#pragma unroll
                for (int reg = 0; reg < 4; ++reg) O[is][dt][reg] *= fr[reg];

            const short8 pa0 = pack8(sp);
            const short8 pa1 = pack8(sp + 8);
#pragma unroll
            for (int dt = 0; dt < 4; ++dt) {
                O[is][dt] = __builtin_amdgcn_mfma_f32_16x16x32_bf16(pa0, vf[dt][0], O[is][dt], 0, 0, 0);
                O[is][dt] = __builtin_amdgcn_mfma_f32_16x16x32_bf16(pa1, vf[dt][1], O[is][dt], 0, 0, 0);
            }
        }
    }

#pragma unroll
    for (int is = 0; is < 4; ++is) {
        const float inv = 1.0f / ll[is];
        float fr[4];
#pragma unroll
        for (int reg = 0; reg < 4; ++reg)
            fr[reg] = __shfl(inv, (l >> 4) * 4 + reg);
#pragma unroll
        for (int dt = 0; dt < 4; ++dt)
#pragma unroll
            for (int reg = 0; reg < 4; ++reg) {
                const int c = i0 + is * 16 + (l >> 4) * 4 + reg;
                hp[((size_t)b * C + c) * DOUT + hh * HD + dt * 16 + lr] =
                    O[is][dt][reg] * fr[reg];
            }
    }
}

// K3: s[c] = tanh(h_prime[c] @ W1^T + b1) @ W2^T + b2, per (b, 64-channel chunk)
__global__ __launch_bounds__(256) void k3_gate(
    const float* __restrict__ hp, const float* __restrict__ W1,
    const float* __restrict__ b1, const float* __restrict__ W2,
    const float* __restrict__ b2, float* __restrict__ sgate)
{
    __shared__ float w1t[256 * 64];  // [k][n], XOR-swizzled, 64 KB
    const int t = threadIdx.x;
    const int b = blockIdx.x >> 3;
    const int c0 = (blockIdx.x & 7) * 64;
#pragma unroll 8
    for (int n = 0; n < 64; ++n)
        w1t[t * 64 + (n ^ (t & 31))] = W1[n * 256 + t];
    __syncthreads();

    const int l = t & 63;
    const int w = t >> 6;
    const float w2v = W2[l];
    const float b2v = b2[0];
    const float b1v = b1[l];
    for (int ci = 0; ci < 16; ++ci) {
        const int c = c0 + w * 16 + ci;
        const float* row = hp + ((size_t)b * C + c) * DOUT;
        float y = b1v;
        for (int k0 = 0; k0 < 256; k0 += 4) {
            float4 hv = *(const float4*)(row + k0);
            y += hv.x * w1t[(k0 + 0) * 64 + (l ^ ((k0 + 0) & 31))]
               + hv.y * w1t[(k0 + 1) * 64 + (l ^ ((k0 + 1) & 31))]
               + hv.z * w1t[(k0 + 2) * 64 + (l ^ ((k0 + 2) & 31))]
               + hv.w * w1t[(k0 + 3) * 64 + (l ^ ((k0 + 3) & 31))];
        }
        float val = tanhf(y) * w2v;
#pragma unroll
        for (int off = 1; off < 64; off <<= 1) val += __shfl_xor(val, off);
        if (l == 0) sgate[b * C + c] = val + b2v;
    }
}

// K4: softmax over channels + weighted sum -> f32 out (reference output dtype is float32)
__global__ __launch_bounds__(256) void k4_out(
    const float* __restrict__ hp, const float* __restrict__ sgate,
    float* __restrict__ out)
{
    __shared__ float wbuf[512];
    __shared__ float red[8];
    const int t = threadIdx.x;
    const int b = blockIdx.x;
    const int l = t & 63, w = t >> 6;
    const float L2E = 1.44269504088896f;

    float s0 = sgate[b * C + t], s1 = sgate[b * C + 256 + t];
    float mx = fmaxf(s0, s1);
#pragma unroll
    for (int off = 1; off < 64; off <<= 1) mx = fmaxf(mx, __shfl_xor(mx, off));
    if (l == 0) red[w] = mx;
    __syncthreads();
    mx = fmaxf(fmaxf(red[0], red[1]), fmaxf(red[2], red[3]));
    float e0 = exp2f((s0 - mx) * L2E), e1 = exp2f((s1 - mx) * L2E);
    float sum = e0 + e1;
#pragma unroll
    for (int off = 1; off < 64; off <<= 1) sum += __shfl_xor(sum, off);
    if (l == 0) red[4 + w] = sum;
    __syncthreads();
    sum = red[4] + red[5] + red[6] + red[7];
    const float inv = 1.f / sum;
    wbuf[t] = e0 * inv;
    wbuf[t + 256] = e1 * inv;
    __syncthreads();

    float acc = 0.f;
    const float* base = hp + (size_t)b * C * DOUT + t;
#pragma unroll 4
    for (int c = 0; c < C; ++c) acc += wbuf[c] * base[(size_t)c * DOUT];
    out[b * DOUT + t] = acc;
}

extern "C" void kernel_launch(void* const* d_in, const int* in_sizes, int n_in,
                              void* d_out, int out_size, void* d_ws, size_t ws_size,
                              hipStream_t stream) {
    const float* hsrc = (const float*)d_in[0];
    const float* Afc  = (const float*)d_in[1];
    const float* W    = (const float*)d_in[2];
    const float* avec = (const float*)d_in[3];
    const float* W1   = (const float*)d_in[4];
    const float* b1   = (const float*)d_in[5];
    const float* W2   = (const float*)d_in[6];
    const float* b2   = (const float*)d_in[7];

    char* ws = (char*)d_ws;
    short* whT = (short*)(ws);                 // 64*4*64*512*2  = 16,777,216 B
    float* ei  = (float*)(ws + 16777216);      // 64*4*512*4     =    524,288 B
    float* ej  = (float*)(ws + 17301504);      // 64*4*512*4     =    524,288 B
    float* hp  = (float*)(ws + 17825792);      // 64*512*256*4   = 33,554,432 B
    float* sg  = (float*)(ws + 51380224);      // 64*512*4       =    131,072 B

    hipLaunchKernelGGL(k1_gemm, dim3(1024), dim3(256), 0, stream, hsrc, W, avec, whT, ei, ej);
    hipLaunchKernelGGL(k2_attn, dim3(512), dim3(256), 0, stream, Afc, whT, ei, ej, hp);
    hipLaunchKernelGGL(k3_gate, dim3(512), dim3(256), 0, stream, hp, W1, b1, W2, b2, sg);
    hipLaunchKernelGGL(k4_out, dim3(64), dim3(256), 0, stream, hp, sg, (float*)d_out);
}

// Round 3
// 188.587 us; speedup vs baseline: 1.5662x; 1.5662x over previous
//
#include <hip/hip_runtime.h>

#define BS 64
#define C 512
#define DIN 256
#define DOUT 256
#define H 4
#define HD 64

typedef __attribute__((ext_vector_type(8))) short short8;
typedef __attribute__((ext_vector_type(4))) float f32x4;

__device__ __forceinline__ short f2bf(float f) {
    union { float f; unsigned u; } v; v.f = f;
    unsigned r = v.u + 0x7fffu + ((v.u >> 16) & 1u);
    return (short)(r >> 16);
}

__device__ __forceinline__ short8 pack8(const float* p) {
    short8 r;
#pragma unroll
    for (int i = 0; i < 8; ++i) r[i] = f2bf(p[i]);
    return r;
}

// K1: Wh = h @ W^T (bf16 MFMA), store WhT[b][h][d][c] bf16 + e_i/e_j[b][h][c] f32
__global__ __launch_bounds__(256) void k1_gemm(
    const float* __restrict__ hsrc, const float* __restrict__ W,
    const float* __restrict__ avec,
    short* __restrict__ whT, float* __restrict__ ei, float* __restrict__ ej)
{
    const int tid = threadIdx.x;
    const int l = tid & 63;
    const int w = tid >> 6;
    const int mtile = blockIdx.x >> 1;
    const int ntile = blockIdx.x & 1;
    const int row_base = mtile * 64 + (w & 1) * 32;     // global row in [0,32768)
    const int col_base = ntile * 128 + (w >> 1) * 64;   // output col in [0,256)
    const int head = col_base >> 6;
    const int lr = l & 15;
    const int kg = (l >> 4) * 8;

    f32x4 acc[2][4];
#pragma unroll
    for (int i = 0; i < 2; ++i)
#pragma unroll
        for (int j = 0; j < 4; ++j) acc[i][j] = f32x4{0.f, 0.f, 0.f, 0.f};

    for (int k0 = 0; k0 < DIN; k0 += 32) {
        short8 af[2];
#pragma unroll
        for (int rt = 0; rt < 2; ++rt) {
            const float* p = hsrc + (size_t)(row_base + rt * 16 + lr) * DIN + k0 + kg;
            float tmp[8];
            *(float4*)(tmp)     = *(const float4*)(p);
            *(float4*)(tmp + 4) = *(const float4*)(p + 4);
            af[rt] = pack8(tmp);
        }
        short8 bfr[4];
#pragma unroll
        for (int ct = 0; ct < 4; ++ct) {
            const float* p = W + (size_t)(col_base + ct * 16 + lr) * DIN + k0 + kg;
            float tmp[8];
            *(float4*)(tmp)     = *(const float4*)(p);
            *(float4*)(tmp + 4) = *(const float4*)(p + 4);
            bfr[ct] = pack8(tmp);
        }
#pragma unroll
        for (int rt = 0; rt < 2; ++rt)
#pragma unroll
            for (int ct = 0; ct < 4; ++ct)
                acc[rt][ct] = __builtin_amdgcn_mfma_f32_16x16x32_bf16(
                    af[rt], bfr[ct], acc[rt][ct], 0, 0, 0);
    }

    float avi[4], avj[4];
#pragma unroll
    for (int ct = 0; ct < 4; ++ct) {
        avi[ct] = avec[head * 2 * HD + ct * 16 + lr];
        avj[ct] = avec[head * 2 * HD + HD + ct * 16 + lr];
    }
#pragma unroll
    for (int rt = 0; rt < 2; ++rt) {
#pragma unroll
        for (int reg = 0; reg < 4; ++reg) {
            const int crow = row_base + rt * 16 + (l >> 4) * 4 + reg;
            const int b = crow >> 9;
            const int c = crow & 511;
            float pi = 0.f, pj = 0.f;
#pragma unroll
            for (int ct = 0; ct < 4; ++ct) {
                const float v = acc[rt][ct][reg];
                pi += v * avi[ct];
                pj += v * avj[ct];
                const int d = ct * 16 + lr;
                whT[((size_t)(b * H + head) * HD + d) * C + c] = f2bf(v);
            }
#pragma unroll
            for (int off = 1; off < 16; off <<= 1) {
                pi += __shfl_xor(pi, off);
                pj += __shfl_xor(pj, off);
            }
            if (lr == 0) {
                ei[(b * H + head) * C + c] = pi;
                ej[(b * H + head) * C + c] = pj;
            }
        }
    }
}

// K2: per (b, 64-row i-tile) block; wave = head. Online softmax + P@V via MFMA.
__global__ __launch_bounds__(256) void k2_attn(
    const float* __restrict__ Afc, const short* __restrict__ whT,
    const float* __restrict__ ei, const float* __restrict__ ej,
    float* __restrict__ hp)
{
    const int tid = threadIdx.x;
    const int l = tid & 63;
    const int hh = tid >> 6;
    const int b = blockIdx.x >> 3;
    const int i0 = (blockIdx.x & 7) * 64;
    const int lr = l & 15;
    const int kg = (l >> 4) * 8;
    const float L2E = 1.44269504088896f;

    f32x4 O[4][4];
#pragma unroll
    for (int is = 0; is < 4; ++is)
#pragma unroll
        for (int dt = 0; dt < 4; ++dt) O[is][dt] = f32x4{0.f, 0.f, 0.f, 0.f};
    float m[4], ll[4];
#pragma unroll
    for (int is = 0; is < 4; ++is) { m[is] = -1e30f; ll[is] = 0.f; }

    float eiv[4];
#pragma unroll
    for (int is = 0; is < 4; ++is)
        eiv[is] = ei[(b * H + hh) * C + i0 + is * 16 + lr];

    const float* ejb = ej + (b * H + hh) * C;
    const short* vb = whT + (size_t)(b * H + hh) * HD * C;

    for (int jt = 0; jt < 8; ++jt) {
        const int j0 = jt * 64;
        float ejv[16];
        *(float4*)(ejv)      = *(const float4*)(ejb + j0 + kg);
        *(float4*)(ejv + 4)  = *(const float4*)(ejb + j0 + kg + 4);
        *(float4*)(ejv + 8)  = *(const float4*)(ejb + j0 + 32 + kg);
        *(float4*)(ejv + 12) = *(const float4*)(ejb + j0 + 32 + kg + 4);

        short8 vf[4][2];
#pragma unroll
        for (int dt = 0; dt < 4; ++dt) {
            const short* p = vb + (size_t)(dt * 16 + lr) * C + j0 + kg;
            vf[dt][0] = *(const short8*)(p);
            vf[dt][1] = *(const short8*)(p + 32);
        }

#pragma unroll
        for (int is = 0; is < 4; ++is) {
            const int i = i0 + is * 16 + lr;
            const float* ap = Afc + ((size_t)b * C + i) * C + j0 + kg;
            float av[16];
            *(float4*)(av)      = *(const float4*)(ap);
            *(float4*)(av + 4)  = *(const float4*)(ap + 4);
            *(float4*)(av + 8)  = *(const float4*)(ap + 32);
            *(float4*)(av + 12) = *(const float4*)(ap + 36);

            float sp[16];
            float tm = -1e30f;
#pragma unroll
            for (int t = 0; t < 16; ++t) {
                float z = eiv[is] + ejv[t];
                z = z > 0.f ? z : 0.2f * z;
                sp[t] = z * av[t];
                tm = fmaxf(tm, sp[t]);
            }
            tm = fmaxf(tm, __shfl_xor(tm, 16));
            tm = fmaxf(tm, __shfl_xor(tm, 32));
            const float mn = fmaxf(m[is], tm);
            const float scale = exp2f((m[is] - mn) * L2E);
            m[is] = mn;
            float ps = 0.f;
#pragma unroll
            for (int t = 0; t < 16; ++t) {
                sp[t] = exp2f((sp[t] - mn) * L2E);
                ps += sp[t];
            }
            ps += __shfl_xor(ps, 16);
            ps += __shfl_xor(ps, 32);
            ll[is] = ll[is] * scale + ps;

            float fr[4];
#pragma unroll
            for (int reg = 0; reg < 4; ++reg)
                fr[reg] = __shfl(scale, (l >> 4) * 4 + reg);
#pragma unroll
            for (int dt = 0; dt < 4; ++dt)
#pragma unroll
                for (int reg = 0; reg < 4; ++reg) O[is][dt][reg] *= fr[reg];

            const short8 pa0 = pack8(sp);
            const short8 pa1 = pack8(sp + 8);
#pragma unroll
            for (int dt = 0; dt < 4; ++dt) {
                O[is][dt] = __builtin_amdgcn_mfma_f32_16x16x32_bf16(pa0, vf[dt][0], O[is][dt], 0, 0, 0);
                O[is][dt] = __builtin_amdgcn_mfma_f32_16x16x32_bf16(pa1, vf[dt][1], O[is][dt], 0, 0, 0);
            }
        }
    }

#pragma unroll
    for (int is = 0; is < 4; ++is) {
        const float inv = 1.0f / ll[is];
        float fr[4];
#pragma unroll
        for (int reg = 0; reg < 4; ++reg)
            fr[reg] = __shfl(inv, (l >> 4) * 4 + reg);
#pragma unroll
        for (int dt = 0; dt < 4; ++dt)
#pragma unroll
            for (int reg = 0; reg < 4; ++reg) {
                const int c = i0 + is * 16 + (l >> 4) * 4 + reg;
                hp[((size_t)b * C + c) * DOUT + hh * HD + dt * 16 + lr] =
                    O[is][dt][reg] * fr[reg];
            }
    }
}

// K3: s[c] = tanh(h_prime[c] @ W1^T + b1) @ W2^T + b2 — MFMA GEMM, no LDS.
// Block = (b, 64-channel tile); wave w owns rows w*16..w*16+15, all 64 cols.
__global__ __launch_bounds__(256) void k3_gate(
    const float* __restrict__ hp, const float* __restrict__ W1,
    const float* __restrict__ b1, const float* __restrict__ W2,
    const float* __restrict__ b2, float* __restrict__ sgate)
{
    const int t = threadIdx.x;
    const int l = t & 63;
    const int w = t >> 6;
    const int b = blockIdx.x >> 3;
    const int c0 = (blockIdx.x & 7) * 64;
    const int lr = l & 15;
    const int kg = (l >> 4) * 8;

    f32x4 acc[4];
#pragma unroll
    for (int ct = 0; ct < 4; ++ct) acc[ct] = f32x4{0.f, 0.f, 0.f, 0.f};

    const float* arow = hp + (size_t)(b * C + c0 + w * 16 + lr) * DOUT;
    for (int k0 = 0; k0 < DOUT; k0 += 32) {
        float ta[8];
        *(float4*)(ta)     = *(const float4*)(arow + k0 + kg);
        *(float4*)(ta + 4) = *(const float4*)(arow + k0 + kg + 4);
        const short8 af = pack8(ta);
#pragma unroll
        for (int ct = 0; ct < 4; ++ct) {
            const float* bp = W1 + (size_t)(ct * 16 + lr) * DOUT + k0 + kg;
            float tb[8];
            *(float4*)(tb)     = *(const float4*)(bp);
            *(float4*)(tb + 4) = *(const float4*)(bp + 4);
            acc[ct] = __builtin_amdgcn_mfma_f32_16x16x32_bf16(af, pack8(tb), acc[ct], 0, 0, 0);
        }
    }

    float b1v[4], w2v[4];
#pragma unroll
    for (int ct = 0; ct < 4; ++ct) {
        b1v[ct] = b1[ct * 16 + lr];
        w2v[ct] = W2[ct * 16 + lr];
    }
    const float b2v = b2[0];
#pragma unroll
    for (int reg = 0; reg < 4; ++reg) {
        float val = 0.f;
#pragma unroll
        for (int ct = 0; ct < 4; ++ct)
            val += tanhf(acc[ct][reg] + b1v[ct]) * w2v[ct];
#pragma unroll
        for (int off = 1; off < 16; off <<= 1) val += __shfl_xor(val, off);
        if (lr == 0)
            sgate[b * C + c0 + w * 16 + (l >> 4) * 4 + reg] = val + b2v;
    }
}

// K4: softmax over channels + weighted sum -> f32 out (reference output dtype is float32)
__global__ __launch_bounds__(256) void k4_out(
    const float* __restrict__ hp, const float* __restrict__ sgate,
    float* __restrict__ out)
{
    __shared__ float wbuf[512];
    __shared__ float red[8];
    const int t = threadIdx.x;
    const int b = blockIdx.x;
    const int l = t & 63, w = t >> 6;
    const float L2E = 1.44269504088896f;

    float s0 = sgate[b * C + t], s1 = sgate[b * C + 256 + t];
    float mx = fmaxf(s0, s1);
#pragma unroll
    for (int off = 1; off < 64; off <<= 1) mx = fmaxf(mx, __shfl_xor(mx, off));
    if (l == 0) red[w] = mx;
    __syncthreads();
    mx = fmaxf(fmaxf(red[0], red[1]), fmaxf(red[2], red[3]));
    float e0 = exp2f((s0 - mx) * L2E), e1 = exp2f((s1 - mx) * L2E);
    float sum = e0 + e1;
#pragma unroll
    for (int off = 1; off < 64; off <<= 1) sum += __shfl_xor(sum, off);
    if (l == 0) red[4 + w] = sum;
    __syncthreads();
    sum = red[4] + red[5] + red[6] + red[7];
    const float inv = 1.f / sum;
    wbuf[t] = e0 * inv;
    wbuf[t + 256] = e1 * inv;
    __syncthreads();

    float acc = 0.f;
    const float* base = hp + (size_t)b * C * DOUT + t;
#pragma unroll 4
    for (int c = 0; c < C; ++c) acc += wbuf[c] * base[(size_t)c * DOUT];
    out[b * DOUT + t] = acc;
}

extern "C" void kernel_launch(void* const* d_in, const int* in_sizes, int n_in,
                              void* d_out, int out_size, void* d_ws, size_t ws_size,
                              hipStream_t stream) {
    const float* hsrc = (const float*)d_in[0];
    const float* Afc  = (const float*)d_in[1];
    const float* W    = (const float*)d_in[2];
    const float* avec = (const float*)d_in[3];
    const float* W1   = (const float*)d_in[4];
    const float* b1   = (const float*)d_in[5];
    const float* W2   = (const float*)d_in[6];
    const float* b2   = (const float*)d_in[7];

    char* ws = (char*)d_ws;
    short* whT = (short*)(ws);                 // 64*4*64*512*2  = 16,777,216 B
    float* ei  = (float*)(ws + 16777216);      // 64*4*512*4     =    524,288 B
    float* ej  = (float*)(ws + 17301504);      // 64*4*512*4     =    524,288 B
    float* hp  = (float*)(ws + 17825792);      // 64*512*256*4   = 33,554,432 B
    float* sg  = (float*)(ws + 51380224);      // 64*512*4       =    131,072 B

    hipLaunchKernelGGL(k1_gemm, dim3(1024), dim3(256), 0, stream, hsrc, W, avec, whT, ei, ej);
    hipLaunchKernelGGL(k2_attn, dim3(512), dim3(256), 0, stream, Afc, whT, ei, ej, hp);
    hipLaunchKernelGGL(k3_gate, dim3(512), dim3(256), 0, stream, hp, W1, b1, W2, b2, sg);
    hipLaunchKernelGGL(k4_out, dim3(64), dim3(256), 0, stream, hp, sg, (float*)d_out);
}

// Round 5
// 183.565 us; speedup vs baseline: 1.6091x; 1.0274x over previous
//
#include <hip/hip_runtime.h>

#define BS 64
#define C 512
#define DIN 256
#define DOUT 256
#define H 4
#define HD 64

typedef __attribute__((ext_vector_type(8))) short short8;
typedef __attribute__((ext_vector_type(4))) float f32x4;

__device__ __forceinline__ short f2bf(float f) {
    union { float f; unsigned u; } v; v.f = f;
    unsigned r = v.u + 0x7fffu + ((v.u >> 16) & 1u);
    return (short)(r >> 16);
}

__device__ __forceinline__ short8 pack8(const float* p) {
    short8 r;
#pragma unroll
    for (int i = 0; i < 8; ++i) r[i] = f2bf(p[i]);
    return r;
}

// pack to bf16 AND accumulate the sum of the ROUNDED values (so the softmax
// denominator matches the numerator's bf16 P exactly -> uniform rounding cancels)
__device__ __forceinline__ short8 pack8_sum(const float* p, float& s) {
    short8 r;
#pragma unroll
    for (int i = 0; i < 8; ++i) {
        const short b = f2bf(p[i]);
        r[i] = b;
        union { unsigned u; float f; } v;
        v.u = ((unsigned)(unsigned short)b) << 16;
        s += v.f;
    }
    return r;
}

// K1: Wh = h @ W^T (bf16 MFMA), store WhT[b][h][d][c] bf16 + e_i/e_j[b][h][c] f32
__global__ __launch_bounds__(256) void k1_gemm(
    const float* __restrict__ hsrc, const float* __restrict__ W,
    const float* __restrict__ avec,
    short* __restrict__ whT, float* __restrict__ ei, float* __restrict__ ej)
{
    const int tid = threadIdx.x;
    const int l = tid & 63;
    const int w = tid >> 6;
    const int mtile = blockIdx.x >> 1;
    const int ntile = blockIdx.x & 1;
    const int row_base = mtile * 64 + (w & 1) * 32;     // global row in [0,32768)
    const int col_base = ntile * 128 + (w >> 1) * 64;   // output col in [0,256)
    const int head = col_base >> 6;
    const int lr = l & 15;
    const int kg = (l >> 4) * 8;

    f32x4 acc[2][4];
#pragma unroll
    for (int i = 0; i < 2; ++i)
#pragma unroll
        for (int j = 0; j < 4; ++j) acc[i][j] = f32x4{0.f, 0.f, 0.f, 0.f};

    for (int k0 = 0; k0 < DIN; k0 += 32) {
        short8 af[2];
#pragma unroll
        for (int rt = 0; rt < 2; ++rt) {
            const float* p = hsrc + (size_t)(row_base + rt * 16 + lr) * DIN + k0 + kg;
            float tmp[8];
            *(float4*)(tmp)     = *(const float4*)(p);
            *(float4*)(tmp + 4) = *(const float4*)(p + 4);
            af[rt] = pack8(tmp);
        }
        short8 bfr[4];
#pragma unroll
        for (int ct = 0; ct < 4; ++ct) {
            const float* p = W + (size_t)(col_base + ct * 16 + lr) * DIN + k0 + kg;
            float tmp[8];
            *(float4*)(tmp)     = *(const float4*)(p);
            *(float4*)(tmp + 4) = *(const float4*)(p + 4);
            bfr[ct] = pack8(tmp);
        }
#pragma unroll
        for (int rt = 0; rt < 2; ++rt)
#pragma unroll
            for (int ct = 0; ct < 4; ++ct)
                acc[rt][ct] = __builtin_amdgcn_mfma_f32_16x16x32_bf16(
                    af[rt], bfr[ct], acc[rt][ct], 0, 0, 0);
    }

    float avi[4], avj[4];
#pragma unroll
    for (int ct = 0; ct < 4; ++ct) {
        avi[ct] = avec[head * 2 * HD + ct * 16 + lr];
        avj[ct] = avec[head * 2 * HD + HD + ct * 16 + lr];
    }
#pragma unroll
    for (int rt = 0; rt < 2; ++rt) {
#pragma unroll
        for (int reg = 0; reg < 4; ++reg) {
            const int crow = row_base + rt * 16 + (l >> 4) * 4 + reg;
            const int b = crow >> 9;
            const int c = crow & 511;
            float pi = 0.f, pj = 0.f;
#pragma unroll
            for (int ct = 0; ct < 4; ++ct) {
                const float v = acc[rt][ct][reg];
                pi += v * avi[ct];
                pj += v * avj[ct];
                const int d = ct * 16 + lr;
                whT[((size_t)(b * H + head) * HD + d) * C + c] = f2bf(v);
            }
#pragma unroll
            for (int off = 1; off < 16; off <<= 1) {
                pi += __shfl_xor(pi, off);
                pj += __shfl_xor(pj, off);
            }
            if (lr == 0) {
                ei[(b * H + head) * C + c] = pi;
                ej[(b * H + head) * C + c] = pj;
            }
        }
    }
}

// K2: per (b, 32-row i-tile) block; wave = head. Non-online softmax (scores bounded:
// |leaky(ei+ej)*A| <~ 8.5, exp <= ~5000, safe in f32/bf16 range) -> single pass.
// Grid 1024 with bijective XCD swizzle so same-b blocks share an XCD L2 for V.
__global__ __launch_bounds__(256) void k2_attn(
    const float* __restrict__ Afc, const short* __restrict__ whT,
    const float* __restrict__ ei, const float* __restrict__ ej,
    float* __restrict__ hp)
{
    const int tid = threadIdx.x;
    const int l = tid & 63;
    const int hh = tid >> 6;
    // nwg=1024, 8 XCDs, 128 blocks/XCD: work = (bid%8)*128 + bid/8 (bijective)
    const int swz = (blockIdx.x & 7) * 128 + (blockIdx.x >> 3);
    const int b = swz >> 4;
    const int i0 = (swz & 15) * 32;
    const int lr = l & 15;
    const int kg = (l >> 4) * 8;
    const float L2E = 1.44269504088896f;

    f32x4 O[2][4];
#pragma unroll
    for (int is = 0; is < 2; ++is)
#pragma unroll
        for (int dt = 0; dt < 4; ++dt) O[is][dt] = f32x4{0.f, 0.f, 0.f, 0.f};
    float lsum[2] = {0.f, 0.f};

    float eiv[2];
#pragma unroll
    for (int is = 0; is < 2; ++is)
        eiv[is] = ei[(b * H + hh) * C + i0 + is * 16 + lr] * L2E;

    const float* ejb = ej + (b * H + hh) * C;
    const short* vb = whT + (size_t)(b * H + hh) * HD * C;

    for (int jt = 0; jt < 8; ++jt) {
        const int j0 = jt * 64;
        float ejv[16];
        *(float4*)(ejv)      = *(const float4*)(ejb + j0 + kg);
        *(float4*)(ejv + 4)  = *(const float4*)(ejb + j0 + kg + 4);
        *(float4*)(ejv + 8)  = *(const float4*)(ejb + j0 + 32 + kg);
        *(float4*)(ejv + 12) = *(const float4*)(ejb + j0 + 32 + kg + 4);
#pragma unroll
        for (int t = 0; t < 16; ++t) ejv[t] *= L2E;

        short8 vf[4][2];
#pragma unroll
        for (int dt = 0; dt < 4; ++dt) {
            const short* p = vb + (size_t)(dt * 16 + lr) * C + j0 + kg;
            vf[dt][0] = *(const short8*)(p);
            vf[dt][1] = *(const short8*)(p + 32);
        }

#pragma unroll
        for (int is = 0; is < 2; ++is) {
            const int i = i0 + is * 16 + lr;
            const float* ap = Afc + ((size_t)b * C + i) * C + j0 + kg;
            float av[16];
            *(float4*)(av)      = *(const float4*)(ap);
            *(float4*)(av + 4)  = *(const float4*)(ap + 4);
            *(float4*)(av + 8)  = *(const float4*)(ap + 32);
            *(float4*)(av + 12) = *(const float4*)(ap + 36);

            float sp[16];
#pragma unroll
            for (int t = 0; t < 16; ++t) {
                // eiv/ejv carry log2(e); leaky_relu is positively homogeneous
                const float z = eiv[is] + ejv[t];
                const float zl = fmaxf(z, 0.2f * z);
                sp[t] = exp2f(zl * av[t]);
            }

            const short8 pa0 = pack8_sum(sp, lsum[is]);
            const short8 pa1 = pack8_sum(sp + 8, lsum[is]);
#pragma unroll
            for (int dt = 0; dt < 4; ++dt) {
                O[is][dt] = __builtin_amdgcn_mfma_f32_16x16x32_bf16(pa0, vf[dt][0], O[is][dt], 0, 0, 0);
                O[is][dt] = __builtin_amdgcn_mfma_f32_16x16x32_bf16(pa1, vf[dt][1], O[is][dt], 0, 0, 0);
            }
        }
    }

#pragma unroll
    for (int is = 0; is < 2; ++is) {
        lsum[is] += __shfl_xor(lsum[is], 16);
        lsum[is] += __shfl_xor(lsum[is], 32);
        const float inv = 1.0f / lsum[is];
        float fr[4];
#pragma unroll
        for (int reg = 0; reg < 4; ++reg)
            fr[reg] = __shfl(inv, (l >> 4) * 4 + reg);
#pragma unroll
        for (int dt = 0; dt < 4; ++dt)
#pragma unroll
            for (int reg = 0; reg < 4; ++reg) {
                const int c = i0 + is * 16 + (l >> 4) * 4 + reg;
                hp[((size_t)b * C + c) * DOUT + hh * HD + dt * 16 + lr] =
                    O[is][dt][reg] * fr[reg];
            }
    }
}

// K3: s[c] = tanh(h_prime[c] @ W1^T + b1) @ W2^T + b2 — MFMA GEMM, no LDS.
__global__ __launch_bounds__(256) void k3_gate(
    const float* __restrict__ hp, const float* __restrict__ W1,
    const float* __restrict__ b1, const float* __restrict__ W2,
    const float* __restrict__ b2, float* __restrict__ sgate)
{
    const int t = threadIdx.x;
    const int l = t & 63;
    const int w = t >> 6;
    const int b = blockIdx.x >> 3;
    const int c0 = (blockIdx.x & 7) * 64;
    const int lr = l & 15;
    const int kg = (l >> 4) * 8;

    f32x4 acc[4];
#pragma unroll
    for (int ct = 0; ct < 4; ++ct) acc[ct] = f32x4{0.f, 0.f, 0.f, 0.f};

    const float* arow = hp + (size_t)(b * C + c0 + w * 16 + lr) * DOUT;
    for (int k0 = 0; k0 < DOUT; k0 += 32) {
        float ta[8];
        *(float4*)(ta)     = *(const float4*)(arow + k0 + kg);
        *(float4*)(ta + 4) = *(const float4*)(arow + k0 + kg + 4);
        const short8 af = pack8(ta);
#pragma unroll
        for (int ct = 0; ct < 4; ++ct) {
            const float* bp = W1 + (size_t)(ct * 16 + lr) * DOUT + k0 + kg;
            float tb[8];
            *(float4*)(tb)     = *(const float4*)(bp);
            *(float4*)(tb + 4) = *(const float4*)(bp + 4);
            acc[ct] = __builtin_amdgcn_mfma_f32_16x16x32_bf16(af, pack8(tb), acc[ct], 0, 0, 0);
        }
    }

    float b1v[4], w2v[4];
#pragma unroll
    for (int ct = 0; ct < 4; ++ct) {
        b1v[ct] = b1[ct * 16 + lr];
        w2v[ct] = W2[ct * 16 + lr];
    }
    const float b2v = b2[0];
#pragma unroll
    for (int reg = 0; reg < 4; ++reg) {
        float val = 0.f;
#pragma unroll
        for (int ct = 0; ct < 4; ++ct)
            val += tanhf(acc[ct][reg] + b1v[ct]) * w2v[ct];
#pragma unroll
        for (int off = 1; off < 16; off <<= 1) val += __shfl_xor(val, off);
        if (lr == 0)
            sgate[b * C + c0 + w * 16 + (l >> 4) * 4 + reg] = val + b2v;
    }
}

// K4: softmax over channels + weighted sum -> f32 out
__global__ __launch_bounds__(256) void k4_out(
    const float* __restrict__ hp, const float* __restrict__ sgate,
    float* __restrict__ out)
{
    __shared__ float wbuf[512];
    __shared__ float red[8];
    const int t = threadIdx.x;
    const int b = blockIdx.x;
    const int l = t & 63, w = t >> 6;
    const float L2E = 1.44269504088896f;

    float s0 = sgate[b * C + t], s1 = sgate[b * C + 256 + t];
    float mx = fmaxf(s0, s1);
#pragma unroll
    for (int off = 1; off < 64; off <<= 1) mx = fmaxf(mx, __shfl_xor(mx, off));
    if (l == 0) red[w] = mx;
    __syncthreads();
    mx = fmaxf(fmaxf(red[0], red[1]), fmaxf(red[2], red[3]));
    float e0 = exp2f((s0 - mx) * L2E), e1 = exp2f((s1 - mx) * L2E);
    float sum = e0 + e1;
#pragma unroll
    for (int off = 1; off < 64; off <<= 1) sum += __shfl_xor(sum, off);
    if (l == 0) red[4 + w] = sum;
    __syncthreads();
    sum = red[4] + red[5] + red[6] + red[7];
    const float inv = 1.f / sum;
    wbuf[t] = e0 * inv;
    wbuf[t + 256] = e1 * inv;
    __syncthreads();

    float acc = 0.f;
    const float* base = hp + (size_t)b * C * DOUT + t;
#pragma unroll 4
    for (int c = 0; c < C; ++c) acc += wbuf[c] * base[(size_t)c * DOUT];
    out[b * DOUT + t] = acc;
}

extern "C" void kernel_launch(void* const* d_in, const int* in_sizes, int n_in,
                              void* d_out, int out_size, void* d_ws, size_t ws_size,
                              hipStream_t stream) {
    const float* hsrc = (const float*)d_in[0];
    const float* Afc  = (const float*)d_in[1];
    const float* W    = (const float*)d_in[2];
    const float* avec = (const float*)d_in[3];
    const float* W1   = (const float*)d_in[4];
    const float* b1   = (const float*)d_in[5];
    const float* W2   = (const float*)d_in[6];
    const float* b2   = (const float*)d_in[7];

    char* ws = (char*)d_ws;
    short* whT = (short*)(ws);                 // 64*4*64*512*2  = 16,777,216 B
    float* ei  = (float*)(ws + 16777216);      // 64*4*512*4     =    524,288 B
    float* ej  = (float*)(ws + 17301504);      // 64*4*512*4     =    524,288 B
    float* hp  = (float*)(ws + 17825792);      // 64*512*256*4   = 33,554,432 B
    float* sg  = (float*)(ws + 51380224);      // 64*512*4       =    131,072 B

    hipLaunchKernelGGL(k1_gemm, dim3(1024), dim3(256), 0, stream, hsrc, W, avec, whT, ei, ej);
    hipLaunchKernelGGL(k2_attn, dim3(1024), dim3(256), 0, stream, Afc, whT, ei, ej, hp);
    hipLaunchKernelGGL(k3_gate, dim3(512), dim3(256), 0, stream, hp, W1, b1, W2, b2, sg);
    hipLaunchKernelGGL(k4_out, dim3(64), dim3(256), 0, stream, hp, sg, (float*)d_out);
}